// Round 3
// baseline (12477.595 us; speedup 1.0000x reference)
//
#include <hip/hip_runtime.h>
#include <hip/hip_bf16.h>
#include <stdint.h>

// Problem constants: B=64, S=512, D=1024, H=1024, O=1024
#define BB   64
#define SS   512
#define DD   1024
#define HH   1024
#define TH3  3072   // 3*H
#define TCH  32     // timestep chunk for Gx precompute / persistent segment

using frag8 = __attribute__((ext_vector_type(8))) short;   // 8 bf16
using f32x4 = __attribute__((ext_vector_type(4))) float;

#define MFMA_BF16(a, b, c) __builtin_amdgcn_mfma_f32_16x16x32_bf16(a, b, c, 0, 0, 0)

__device__ __forceinline__ void split_bf16(float v, short& hi, short& lo) {
    uint32_t u = __float_as_uint(v);
    uint32_t uh = u & 0xFFFF0000u;          // truncate to bf16
    float fl = v - __uint_as_float(uh);     // exact residual
    hi = (short)(uh >> 16);
    lo = (short)(__float_as_uint(fl) >> 16);
}

// ---------------------------------------------------------------------------
// W pre-transform: Wg [2048, 3072] fp32 -> Wt_hi/Wt_lo bf16 in MFMA B-fragment
// order. Fragment f = (jb*3 + g)*64 + kt covers k = kt*32 + quad*8 + j,
// n(col) = g*1024 + jb*16 + (lane&15). Stored as Wt[f*512 + lane*8 + j].
// kt 0..31 = x rows (0..1023), kt 32..63 = h rows (1024..2047).
// ---------------------------------------------------------------------------
__global__ __launch_bounds__(256) void prep_w(
    const float* __restrict__ Wg, short* __restrict__ Wt_hi,
    short* __restrict__ Wt_lo)
{
    int idx = blockIdx.x * 256 + threadIdx.x;   // 0 .. 786431
    int lane = idx & 63;
    int f = idx >> 6;            // 0..12287
    int kt = f & 63;
    int fg = f >> 6;
    int g = fg % 3;
    int jb = fg / 3;
    int krow = kt * 32 + (lane >> 4) * 8;
    int col = g * HH + jb * 16 + (lane & 15);
    size_t dst = (size_t)f * 512 + (size_t)lane * 8;
#pragma unroll
    for (int j = 0; j < 8; ++j) {
        float v = Wg[(size_t)(krow + j) * TH3 + col];
        short hi, lo;
        split_bf16(v, hi, lo);
        Wt_hi[dst + j] = hi;
        Wt_lo[dst + j] = lo;
    }
}

// ---------------------------------------------------------------------------
// Wc pre-transform: Wc [1024,1024] fp32 -> B-fragment order, f = jb*32 + kt.
// ---------------------------------------------------------------------------
__global__ __launch_bounds__(256) void prep_wc(
    const float* __restrict__ Wc, short* __restrict__ Wct_hi,
    short* __restrict__ Wct_lo)
{
    int idx = blockIdx.x * 256 + threadIdx.x;   // 0 .. 131071
    int lane = idx & 63;
    int f = idx >> 6;            // 0..2047
    int kt = f & 31;
    int jb = f >> 5;
    int krow = kt * 32 + (lane >> 4) * 8;
    int col = jb * 16 + (lane & 15);
    size_t dst = (size_t)f * 512 + (size_t)lane * 8;
#pragma unroll
    for (int j = 0; j < 8; ++j) {
        float v = Wc[(size_t)(krow + j) * HH + col];
        short hi, lo;
        split_bf16(v, hi, lo);
        Wct_hi[dst + j] = hi;
        Wct_lo[dst + j] = lo;
    }
}

// ---------------------------------------------------------------------------
// Gx precompute: gx[tl, m, :] = x[m, t0+tl, :] @ Wg[0:1024, :] + bg
// Grid = 32 tl x 16 jbg (jbg fastest -> same-jbg same XCD, W slice stays
// L2-resident across tl). 4 waves: wave w covers 2 m-frags x 2 jb.
// ---------------------------------------------------------------------------
__global__ __launch_bounds__(256) void gx_gemm(
    const short* __restrict__ Wt_hi, const short* __restrict__ Wt_lo,
    const float* __restrict__ x,        // [B, S, D] fp32
    const float* __restrict__ bg,       // [3H]
    float* __restrict__ gx,             // [TCH, B, 3H] fp32
    int t0)
{
    const int tid = threadIdx.x;
    const int lane = tid & 63;
    const int w = tid >> 6;
    const int jbg = blockIdx.x & 15;
    const int tl = blockIdx.x >> 4;
    const int t = t0 + tl;
    const int m0 = (w & 1) * 32;
    const int jbb = jbg * 4 + (w >> 1) * 2;
    const int kq = (lane >> 4) * 8;

    f32x4 acc[2][2][3];
#pragma unroll
    for (int mi = 0; mi < 2; ++mi)
#pragma unroll
        for (int jp = 0; jp < 2; ++jp)
#pragma unroll
            for (int g = 0; g < 3; ++g)
                acc[mi][jp][g] = (f32x4){0.f, 0.f, 0.f, 0.f};

    const float* xr0 = x + ((size_t)(m0 + (lane & 15)) * SS + t) * DD;
    const float* xr1 = xr0 + (size_t)16 * SS * DD;

    for (int kt = 0; kt < 32; ++kt) {
        frag8 ah[2], al[2];
#pragma unroll
        for (int mi = 0; mi < 2; ++mi) {
            const float* xp = (mi == 0 ? xr0 : xr1) + kt * 32 + kq;
            float xv[8];
            *(float4*)&xv[0] = *(const float4*)xp;
            *(float4*)&xv[4] = *(const float4*)(xp + 4);
#pragma unroll
            for (int j = 0; j < 8; ++j) {
                short hi, lo;
                split_bf16(xv[j], hi, lo);
                ah[mi][j] = hi;
                al[mi][j] = lo;
            }
        }
#pragma unroll
        for (int jp = 0; jp < 2; ++jp) {
#pragma unroll
            for (int g = 0; g < 3; ++g) {
                size_t base =
                    (((size_t)(jbb + jp) * 3 + g) * 64 + kt) * 512 + (size_t)lane * 8;
                frag8 bh = *(const frag8*)(Wt_hi + base);
                frag8 bl = *(const frag8*)(Wt_lo + base);
#pragma unroll
                for (int mi = 0; mi < 2; ++mi) {
                    f32x4 a = acc[mi][jp][g];
                    a = MFMA_BF16(ah[mi], bh, a);
                    a = MFMA_BF16(ah[mi], bl, a);
                    a = MFMA_BF16(al[mi], bh, a);
                    acc[mi][jp][g] = a;
                }
            }
        }
    }

    const int lcol = lane & 15;
    const int rq = (lane >> 4) * 4;
#pragma unroll
    for (int jp = 0; jp < 2; ++jp) {
        const int col = (jbb + jp) * 16 + lcol;
#pragma unroll
        for (int g = 0; g < 3; ++g) {
            const float bias = bg[g * HH + col];
#pragma unroll
            for (int mi = 0; mi < 2; ++mi) {
#pragma unroll
                for (int reg = 0; reg < 4; ++reg) {
                    int m = m0 + mi * 16 + rq + reg;
                    gx[((size_t)tl * BB + m) * TH3 + g * HH + col] =
                        acc[mi][jp][g][reg] + bias;
                }
            }
        }
    }
}

// ---------------------------------------------------------------------------
// Persistent GRU segment: runs TCH steps in ONE launch.
// Grid = 256 blocks (jb = bid&63 fastest -> same-jb same XCD; mt = bid>>6),
// 512 threads = 8 waves. Wave w owns kt slice w*4..w*4+3 of the h-half of W,
// held in REGISTERS across all TCH steps (24 frag8 = 96 VGPRs). Per step:
// 36 reg-fed MFMAs, 8-way K-reduce through LDS, epilogue by waves 0-3, then
// a 64-block mt-group barrier (monotonic counter, agent-scope atomics).
// Double-buffered h means one barrier per step suffices: a block signals
// only after its step-t reads AND writes are drained (vmcnt0 at barrier).
// ---------------------------------------------------------------------------
__global__ __launch_bounds__(512, 2) void gru_seg(
    const short* __restrict__ Wt_hi, const short* __restrict__ Wt_lo,
    const float* __restrict__ gx,       // [TCH, B, 3H]
    float* __restrict__ h0f, short* __restrict__ h0hi, short* __restrict__ h0lo,
    float* __restrict__ h1f, short* __restrict__ h1hi, short* __restrict__ h1lo,
    __hip_bfloat16* __restrict__ hs,    // [B, S, H]
    int* __restrict__ cnt,              // [4 * 32] ints, one cacheline per mt
    int t0)
{
    __shared__ float red[24][256];      // [w*3+g][lane*4+reg]

    const int tid = threadIdx.x;
    const int lane = tid & 63;
    const int w = tid >> 6;             // 0..7
    const int jb = blockIdx.x & 63;
    const int mt = blockIdx.x >> 6;
    const int m0 = mt * 16;
    const int kq = (lane >> 4) * 8;
    const int mrow = m0 + (lane & 15);
    const size_t rowoff = (size_t)mrow * HH;

    // ---- load this wave's W-h fragments into registers (held all segment) ----
    frag8 bh[3][4], bl[3][4];
    {
        const size_t fbase = (size_t)jb * 3 * 64;
#pragma unroll
        for (int g = 0; g < 3; ++g)
#pragma unroll
            for (int i = 0; i < 4; ++i) {
                size_t base = (fbase + (size_t)g * 64 + 32 + (w * 4 + i)) * 512
                              + (size_t)lane * 8;
                bh[g][i] = *(const frag8*)(Wt_hi + base);
                bl[g][i] = *(const frag8*)(Wt_lo + base);
            }
    }

    // epilogue mapping: thread tid<256 owns output (row = (lv>>4)*4+reg,
    // col = lv&15) of the 16x16 tile; matches C-layout col=lane&15,
    // row=quad*4+reg via tid = lane*4+reg.
    const int lv = tid >> 2;
    const int reg = tid & 3;
    const int ecol = jb * 16 + (lv & 15);
    const int em = m0 + ((lv >> 4) << 2) + reg;
    const size_t eoff = (size_t)em * HH + ecol;
    int* cnt_mt = cnt + mt * 32;

    for (int tl = 0; tl < TCH; ++tl) {
        const int t = t0 + tl;
        const int cur = tl & 1;         // 0: read set0 write set1
        const short* hrh = (cur ? h1hi : h0hi) + rowoff;
        const short* hrl = (cur ? h1lo : h0lo) + rowoff;

        // hoisted epilogue operands (latency hides under MFMAs + reduce)
        float gxr = 0.f, gxz = 0.f, gxnn = 0.f, hold = 0.f;
        if (tid < 256) {
            const float* gp = gx + ((size_t)tl * BB + em) * TH3 + ecol;
            gxr = gp[0];
            gxz = gp[HH];
            gxnn = gp[2 * HH];
            hold = (cur ? h1f : h0f)[eoff];
        }

        frag8 ah[4], al[4];
#pragma unroll
        for (int i = 0; i < 4; ++i) {
            const int kt = w * 4 + i;
            ah[i] = *(const frag8*)(hrh + kt * 32 + kq);
            al[i] = *(const frag8*)(hrl + kt * 32 + kq);
        }

        f32x4 accr = {0.f, 0.f, 0.f, 0.f};
        f32x4 accz = {0.f, 0.f, 0.f, 0.f};
        f32x4 accn = {0.f, 0.f, 0.f, 0.f};
#pragma unroll
        for (int i = 0; i < 4; ++i) {
            accr = MFMA_BF16(ah[i], bh[0][i], accr);
            accr = MFMA_BF16(ah[i], bl[0][i], accr);
            accr = MFMA_BF16(al[i], bh[0][i], accr);
            accz = MFMA_BF16(ah[i], bh[1][i], accz);
            accz = MFMA_BF16(ah[i], bl[1][i], accz);
            accz = MFMA_BF16(al[i], bh[1][i], accz);
            accn = MFMA_BF16(ah[i], bh[2][i], accn);
            accn = MFMA_BF16(ah[i], bl[2][i], accn);
            accn = MFMA_BF16(al[i], bh[2][i], accn);
        }

        *(f32x4*)&red[w * 3 + 0][lane * 4] = accr;
        *(f32x4*)&red[w * 3 + 1][lane * 4] = accz;
        *(f32x4*)&red[w * 3 + 2][lane * 4] = accn;
        __syncthreads();

        if (tid < 256) {
            float rg = gxr, zg = gxz, ng = gxnn;
#pragma unroll
            for (int ww = 0; ww < 8; ++ww) {
                rg += red[ww * 3 + 0][tid];
                zg += red[ww * 3 + 1][tid];
                ng += red[ww * 3 + 2][tid];
            }
            float r = 1.f / (1.f + __expf(-rg));
            float z = 1.f / (1.f + __expf(-zg));
            float na = ng + r * hold;
            float n = 1.f - 2.f / (1.f + __expf(2.f * na));   // tanh(na)
            float hn = (1.f - z) * n + z * hold;

            (cur ? h0f : h1f)[eoff] = hn;
            short hi, lo;
            split_bf16(hn, hi, lo);
            (cur ? h0hi : h1hi)[eoff] = hi;
            (cur ? h0lo : h1lo)[eoff] = lo;
            hs[((size_t)em * SS + t) * HH + ecol] = __float2bfloat16(hn);
        }
        __syncthreads();   // drains all block stores (vmcnt0) + protects red

        // ---- 64-block mt-group barrier (monotonic counter across whole run) ----
        if (tid == 0) {
            __threadfence();   // agent-scope release of the h/hs stores
            __hip_atomic_fetch_add(cnt_mt, 1, __ATOMIC_RELEASE,
                                   __HIP_MEMORY_SCOPE_AGENT);
            const int target = 64 * (t + 1);
            while (__hip_atomic_load(cnt_mt, __ATOMIC_ACQUIRE,
                                     __HIP_MEMORY_SCOPE_AGENT) < target)
                __builtin_amdgcn_s_sleep(1);
        }
        __syncthreads();
    }
}

// ---------------------------------------------------------------------------
// Output GEMM via MFMA: out[B*S, O] = hs_bf16 @ (Wc_hi + Wc_lo) + bc.
// Block = 128x128 tile, 2x2 waves; each wave 4 m-frags x 4 jb, full K.
// ---------------------------------------------------------------------------
__global__ __launch_bounds__(256) void out_mfma(
    const short* __restrict__ Wct_hi, const short* __restrict__ Wct_lo,
    const __hip_bfloat16* __restrict__ hs,   // [B*S, H] bf16
    const float* __restrict__ bc, float* __restrict__ out)
{
    const int tid = threadIdx.x;
    const int lane = tid & 63;
    const int w = tid >> 6;
    const int nb = blockIdx.x & 7;
    const int mb = blockIdx.x >> 3;
    const int r0 = mb * 128 + (w & 1) * 64;     // wave row base
    const int jb0 = nb * 8 + (w >> 1) * 4;      // wave global-jb base
    const int kq = (lane >> 4) * 8;

    f32x4 acc[4][4];
#pragma unroll
    for (int i = 0; i < 4; ++i)
#pragma unroll
        for (int j = 0; j < 4; ++j) acc[i][j] = (f32x4){0.f, 0.f, 0.f, 0.f};

    const short* ar[4];
#pragma unroll
    for (int i = 0; i < 4; ++i)
        ar[i] = (const short*)hs +
                (size_t)(r0 + i * 16 + (lane & 15)) * HH + kq;

    for (int kt = 0; kt < 32; ++kt) {
        frag8 a[4];
#pragma unroll
        for (int i = 0; i < 4; ++i)
            a[i] = *(const frag8*)(ar[i] + kt * 32);
#pragma unroll
        for (int j = 0; j < 4; ++j) {
            size_t base = ((size_t)(jb0 + j) * 32 + kt) * 512 + (size_t)lane * 8;
            frag8 bhf = *(const frag8*)(Wct_hi + base);
            frag8 blf = *(const frag8*)(Wct_lo + base);
#pragma unroll
            for (int i = 0; i < 4; ++i) {
                acc[i][j] = MFMA_BF16(a[i], bhf, acc[i][j]);
                acc[i][j] = MFMA_BF16(a[i], blf, acc[i][j]);
            }
        }
    }

    const int lcol = lane & 15;
    const int rq = (lane >> 4) * 4;
#pragma unroll
    for (int j = 0; j < 4; ++j) {
        const int col = (jb0 + j) * 16 + lcol;
        const float bias = bc[col];
#pragma unroll
        for (int i = 0; i < 4; ++i) {
#pragma unroll
            for (int reg = 0; reg < 4; ++reg) {
                int row = r0 + i * 16 + rq + reg;
                out[(size_t)row * HH + col] = acc[i][j][reg] + bias;
            }
        }
    }
}

// ---------------------------------------------------------------------------
extern "C" void kernel_launch(void* const* d_in, const int* in_sizes, int n_in,
                              void* d_out, int out_size, void* d_ws, size_t ws_size,
                              hipStream_t stream) {
    const float* x  = (const float*)d_in[0];   // [B, S, D]
    const float* Wg = (const float*)d_in[1];   // [D+H, 3H]
    const float* bg = (const float*)d_in[2];   // [3H]
    const float* Wc = (const float*)d_in[3];   // [H, O]
    const float* bc = (const float*)d_in[4];   // [O]
    float* out = (float*)d_out;                // [B, S, O]

    // Workspace layout (~118.5 MB):
    //   hs    : [B,S,H] bf16                       67,108,864 B
    //   Wt_hi : [2048*3072] bf16 fragment order    12,582,912 B
    //   Wt_lo : same                               12,582,912 B
    //   2 x state set {h fp32, h_hi bf16, h_lo bf16} = 2 x 524,288 B
    //   gx    : [TCH, B, 3H] fp32                  25,165,824 B
    //   cnt   : 4 mt-group barrier counters, 128 B apart       512 B
    //   Wct_hi/Wct_lo (2 MB each) alias gx (gx dead after the loop).
    char* ws = (char*)d_ws;
    __hip_bfloat16* hs = (__hip_bfloat16*)ws;
    short* Wt_hi = (short*)(ws + 67108864);
    short* Wt_lo = (short*)(ws + 67108864 + 12582912);
    char* state = ws + 67108864 + 2 * 12582912;
    const size_t SET = 524288;
    float* gx = (float*)(state + 2 * SET);
    int* cnt = (int*)(state + 2 * SET + 25165824);
    short* Wct_hi = (short*)gx;                  // aliases gx (post-loop only)
    short* Wct_lo = Wct_hi + 1048576;

    float* hf[2];  short* hhi[2]; short* hlo[2];
    for (int p = 0; p < 2; ++p) {
        hf[p]  = (float*)(state + p * SET);
        hhi[p] = (short*)(state + p * SET + 262144);
        hlo[p] = (short*)(state + p * SET + 393216);
    }

    // zero the t=0 state set and the barrier counters (re-done every graph replay)
    hipMemsetAsync(state, 0, SET, stream);
    hipMemsetAsync(cnt, 0, 512, stream);

    prep_w<<<3072, 256, 0, stream>>>(Wg, Wt_hi, Wt_lo);

    for (int t0 = 0; t0 < SS; t0 += TCH) {
        gx_gemm<<<512, 256, 0, stream>>>(Wt_hi, Wt_lo, x, bg, gx, t0);

        const short* a0 = Wt_hi; const short* a1 = Wt_lo;
        const float* a2 = gx;
        float* a3 = hf[0]; short* a4 = hhi[0]; short* a5 = hlo[0];
        float* a6 = hf[1]; short* a7 = hhi[1]; short* a8 = hlo[1];
        __hip_bfloat16* a9 = hs; int* a10 = cnt; int a11 = t0;
        void* args[] = {&a0, &a1, &a2, &a3, &a4, &a5, &a6, &a7, &a8,
                        &a9, &a10, &a11};
        hipError_t ce = hipLaunchCooperativeKernel(
            gru_seg, dim3(256), dim3(512), args, 0, stream);
        if (ce != hipSuccess) {
            // fallback: plain launch — 256 blocks at 1 block/CU co-reside
            gru_seg<<<dim3(256), dim3(512), 0, stream>>>(
                a0, a1, a2, a3, a4, a5, a6, a7, a8, a9, a10, a11);
        }
    }

    {
        prep_wc<<<512, 256, 0, stream>>>(Wc, Wct_hi, Wct_lo);
        out_mfma<<<2048, 256, 0, stream>>>(Wct_hi, Wct_lo, hs, bc, out);
    }
}

// Round 5
// 11471.416 us; speedup vs baseline: 1.0877x; 1.0877x over previous
//
#include <hip/hip_runtime.h>
#include <hip/hip_bf16.h>
#include <stdint.h>

// Problem constants: B=64, S=512, D=1024, H=1024, O=1024
#define BB   64
#define SS   512
#define DD   1024
#define HH   1024
#define TH3  3072   // 3*H
#define TCH  32     // timestep chunk for Gx precompute / persistent segment

using frag8 = __attribute__((ext_vector_type(8))) short;   // 8 bf16
using f32x4 = __attribute__((ext_vector_type(4))) float;

#define MFMA_BF16(a, b, c) __builtin_amdgcn_mfma_f32_16x16x32_bf16(a, b, c, 0, 0, 0)
#define AGENT __HIP_MEMORY_SCOPE_AGENT

__device__ __forceinline__ void split_bf16(float v, short& hi, short& lo) {
    uint32_t u = __float_as_uint(v);
    uint32_t uh = u & 0xFFFF0000u;          // truncate to bf16
    float fl = v - __uint_as_float(uh);     // exact residual
    hi = (short)(uh >> 16);
    lo = (short)(__float_as_uint(fl) >> 16);
}

__device__ __forceinline__ float bf2f(unsigned short u) {
    union { uint32_t i; float f; } v;
    v.i = ((uint32_t)u) << 16;
    return v.f;
}

// ---------------------------------------------------------------------------
// W pre-transform: Wg [2048, 3072] fp32 -> Wt_hi/Wt_lo bf16 in MFMA B-fragment
// order. Fragment f = (jb*3 + g)*64 + kt covers k = kt*32 + quad*8 + j,
// n(col) = g*1024 + jb*16 + (lane&15). Stored as Wt[f*512 + lane*8 + j].
// kt 0..31 = x rows (0..1023), kt 32..63 = h rows (1024..2047).
// ---------------------------------------------------------------------------
__global__ __launch_bounds__(256) void prep_w(
    const float* __restrict__ Wg, short* __restrict__ Wt_hi,
    short* __restrict__ Wt_lo)
{
    int idx = blockIdx.x * 256 + threadIdx.x;   // 0 .. 786431
    int lane = idx & 63;
    int f = idx >> 6;            // 0..12287
    int kt = f & 63;
    int fg = f >> 6;
    int g = fg % 3;
    int jb = fg / 3;
    int krow = kt * 32 + (lane >> 4) * 8;
    int col = g * HH + jb * 16 + (lane & 15);
    size_t dst = (size_t)f * 512 + (size_t)lane * 8;
#pragma unroll
    for (int j = 0; j < 8; ++j) {
        float v = Wg[(size_t)(krow + j) * TH3 + col];
        short hi, lo;
        split_bf16(v, hi, lo);
        Wt_hi[dst + j] = hi;
        Wt_lo[dst + j] = lo;
    }
}

// ---------------------------------------------------------------------------
// Wc pre-transform: Wc [1024,1024] fp32 -> B-fragment order, f = jb*32 + kt.
// ---------------------------------------------------------------------------
__global__ __launch_bounds__(256) void prep_wc(
    const float* __restrict__ Wc, short* __restrict__ Wct_hi,
    short* __restrict__ Wct_lo)
{
    int idx = blockIdx.x * 256 + threadIdx.x;   // 0 .. 131071
    int lane = idx & 63;
    int f = idx >> 6;            // 0..2047
    int kt = f & 31;
    int jb = f >> 5;
    int krow = kt * 32 + (lane >> 4) * 8;
    int col = jb * 16 + (lane & 15);
    size_t dst = (size_t)f * 512 + (size_t)lane * 8;
#pragma unroll
    for (int j = 0; j < 8; ++j) {
        float v = Wc[(size_t)(krow + j) * HH + col];
        short hi, lo;
        split_bf16(v, hi, lo);
        Wct_hi[dst + j] = hi;
        Wct_lo[dst + j] = lo;
    }
}

// ---------------------------------------------------------------------------
// Gx precompute: gx[tl, m, :] = x[m, t0+tl, :] @ Wg[0:1024, :] + bg
// Grid = 32 tl x 16 jbg (jbg fastest -> same-jbg same XCD, W slice stays
// L2-resident across tl). 4 waves: wave w covers 2 m-frags x 2 jb.
// ---------------------------------------------------------------------------
__global__ __launch_bounds__(256) void gx_gemm(
    const short* __restrict__ Wt_hi, const short* __restrict__ Wt_lo,
    const float* __restrict__ x,        // [B, S, D] fp32
    const float* __restrict__ bg,       // [3H]
    float* __restrict__ gx,             // [TCH, B, 3H] fp32
    int t0)
{
    const int tid = threadIdx.x;
    const int lane = tid & 63;
    const int w = tid >> 6;
    const int jbg = blockIdx.x & 15;
    const int tl = blockIdx.x >> 4;
    const int t = t0 + tl;
    const int m0 = (w & 1) * 32;
    const int jbb = jbg * 4 + (w >> 1) * 2;
    const int kq = (lane >> 4) * 8;

    f32x4 acc[2][2][3];
#pragma unroll
    for (int mi = 0; mi < 2; ++mi)
#pragma unroll
        for (int jp = 0; jp < 2; ++jp)
#pragma unroll
            for (int g = 0; g < 3; ++g)
                acc[mi][jp][g] = (f32x4){0.f, 0.f, 0.f, 0.f};

    const float* xr0 = x + ((size_t)(m0 + (lane & 15)) * SS + t) * DD;
    const float* xr1 = xr0 + (size_t)16 * SS * DD;

    for (int kt = 0; kt < 32; ++kt) {
        frag8 ah[2], al[2];
#pragma unroll
        for (int mi = 0; mi < 2; ++mi) {
            const float* xp = (mi == 0 ? xr0 : xr1) + kt * 32 + kq;
            float xv[8];
            *(float4*)&xv[0] = *(const float4*)xp;
            *(float4*)&xv[4] = *(const float4*)(xp + 4);
#pragma unroll
            for (int j = 0; j < 8; ++j) {
                short hi, lo;
                split_bf16(xv[j], hi, lo);
                ah[mi][j] = hi;
                al[mi][j] = lo;
            }
        }
#pragma unroll
        for (int jp = 0; jp < 2; ++jp) {
#pragma unroll
            for (int g = 0; g < 3; ++g) {
                size_t base =
                    (((size_t)(jbb + jp) * 3 + g) * 64 + kt) * 512 + (size_t)lane * 8;
                frag8 bh = *(const frag8*)(Wt_hi + base);
                frag8 bl = *(const frag8*)(Wt_lo + base);
#pragma unroll
                for (int mi = 0; mi < 2; ++mi) {
                    f32x4 a = acc[mi][jp][g];
                    a = MFMA_BF16(ah[mi], bh, a);
                    a = MFMA_BF16(ah[mi], bl, a);
                    a = MFMA_BF16(al[mi], bh, a);
                    acc[mi][jp][g] = a;
                }
            }
        }
    }

    const int lcol = lane & 15;
    const int rq = (lane >> 4) * 4;
#pragma unroll
    for (int jp = 0; jp < 2; ++jp) {
        const int col = (jbb + jp) * 16 + lcol;
#pragma unroll
        for (int g = 0; g < 3; ++g) {
            const float bias = bg[g * HH + col];
#pragma unroll
            for (int mi = 0; mi < 2; ++mi) {
#pragma unroll
                for (int reg = 0; reg < 4; ++reg) {
                    int m = m0 + mi * 16 + rq + reg;
                    gx[((size_t)tl * BB + m) * TH3 + g * HH + col] =
                        acc[mi][jp][g][reg] + bias;
                }
            }
        }
    }
}

// ---------------------------------------------------------------------------
// Persistent GRU segment v3: TCH steps in ONE launch.
// Grid = 256 blocks (jb = bid&63, mt = bid>>6 — batch-row groups of 16 are
// independent recurrences, so sync is per-mt-group of 64 blocks).
// 512 threads = 8 waves; wave w holds kt slice w*4..w*4+3 of the W h-half
// in REGISTERS, pinned with an opaque asm so the compiler cannot
// rematerialize the loads per step (round-3 failure: VGPR=76, W re-read
// from global every step).
// Synchronization = round-3-PROVEN semantics: plain h loads/stores,
// __threadfence() (L2 writeback) before a RELEASE add, coherent spin,
// ACQUIRE invalidate before the next step's h reads. The spin polls
// RELAXED with every-16th ACQUIRE and a hard bound — cannot deadlock
// even if relaxed agent loads are served from a stale L2 (round-4 hang).
// ---------------------------------------------------------------------------
__global__ __launch_bounds__(512, 2) void gru_seg(
    const short* __restrict__ Wt_hi, const short* __restrict__ Wt_lo,
    const float* __restrict__ gx,       // [TCH, B, 3H]
    float* __restrict__ h0f, short* __restrict__ h0hi, short* __restrict__ h0lo,
    float* __restrict__ h1f, short* __restrict__ h1hi, short* __restrict__ h1lo,
    __hip_bfloat16* __restrict__ hs,    // [B, S, H]
    int* __restrict__ cnt,              // [4 * 32] ints, one cacheline per mt
    int t0)
{
    __shared__ float red[24][256];      // [w*3+g][lane*4+reg]

    const int tid = threadIdx.x;
    const int lane = tid & 63;
    const int w = tid >> 6;             // 0..7
    const int jb = blockIdx.x & 63;
    const int mt = blockIdx.x >> 6;
    const int m0 = mt * 16;
    const int kq = (lane >> 4) * 8;
    const int mrow = m0 + (lane & 15);
    const size_t rowoff = (size_t)mrow * HH;

    // ---- W-h fragments -> registers, pinned for the whole segment ----
    frag8 bh[3][4], bl[3][4];
    {
        const size_t fbase = (size_t)jb * 3 * 64;
#pragma unroll
        for (int g = 0; g < 3; ++g)
#pragma unroll
            for (int i = 0; i < 4; ++i) {
                size_t base = (fbase + (size_t)g * 64 + 32 + (w * 4 + i)) * 512
                              + (size_t)lane * 8;
                bh[g][i] = *(const frag8*)(Wt_hi + base);
                bl[g][i] = *(const frag8*)(Wt_lo + base);
            }
    }
    // Opaque pin: values become non-rematerializable -> stay in VGPRs.
#pragma unroll
    for (int g = 0; g < 3; ++g)
#pragma unroll
        for (int i = 0; i < 4; ++i)
            asm volatile("" : "+v"(bh[g][i]), "+v"(bl[g][i]));

    // Epilogue mapping (tid<256): row er = tid>>4, col ec = tid&15 ->
    // coalesced stores. red index for (row er, col ec): lane =
    // ((er>>2)<<4)|ec, reg = er&3, ridx = lane*4+reg.
    const int er = tid >> 4;
    const int ec = tid & 15;
    const int em = m0 + er;
    const int ecol = jb * 16 + ec;
    const size_t eoff = (size_t)em * HH + ecol;
    const int ridx = (((er >> 2) << 4) | ec) * 4 + (er & 3);
    int* cnt_mt = cnt + mt * 32;

    for (int tl = 0; tl < TCH; ++tl) {
        const int t = t0 + tl;
        const int cur = tl & 1;         // read set[cur], write set[cur^1]
        const short* hrh = (cur ? h1hi : h0hi) + rowoff;
        const short* hrl = (cur ? h1lo : h0lo) + rowoff;

        // hoisted epilogue operands (own block's previous writes / gx_gemm
        // output — no cross-XCD freshness needed beyond the barrier's inv)
        float gxr = 0.f, gxz = 0.f, gxnn = 0.f, hold = 0.f;
        if (tid < 256) {
            const float* gp = gx + ((size_t)tl * BB + em) * TH3 + ecol;
            gxr = gp[0];
            gxz = gp[HH];
            gxnn = gp[2 * HH];
            hold = (cur ? h1f : h0f)[eoff];
        }

        frag8 ah[4], al[4];
#pragma unroll
        for (int i = 0; i < 4; ++i) {
            const int kt = w * 4 + i;
            ah[i] = *(const frag8*)(hrh + kt * 32 + kq);
            al[i] = *(const frag8*)(hrl + kt * 32 + kq);
        }

        f32x4 accr = {0.f, 0.f, 0.f, 0.f};
        f32x4 accz = {0.f, 0.f, 0.f, 0.f};
        f32x4 accn = {0.f, 0.f, 0.f, 0.f};
#pragma unroll
        for (int i = 0; i < 4; ++i) {
            accr = MFMA_BF16(ah[i], bh[0][i], accr);
            accr = MFMA_BF16(ah[i], bl[0][i], accr);
            accr = MFMA_BF16(al[i], bh[0][i], accr);
            accz = MFMA_BF16(ah[i], bh[1][i], accz);
            accz = MFMA_BF16(ah[i], bl[1][i], accz);
            accz = MFMA_BF16(al[i], bh[1][i], accz);
            accn = MFMA_BF16(ah[i], bh[2][i], accn);
            accn = MFMA_BF16(ah[i], bl[2][i], accn);
            accn = MFMA_BF16(al[i], bh[2][i], accn);
        }

        *(f32x4*)&red[w * 3 + 0][lane * 4] = accr;
        *(f32x4*)&red[w * 3 + 1][lane * 4] = accz;
        *(f32x4*)&red[w * 3 + 2][lane * 4] = accn;
        __syncthreads();

        if (tid < 256) {
            float rg = gxr, zg = gxz, ng = gxnn;
#pragma unroll
            for (int ww = 0; ww < 8; ++ww) {
                rg += red[ww * 3 + 0][ridx];
                zg += red[ww * 3 + 1][ridx];
                ng += red[ww * 3 + 2][ridx];
            }
            float r = 1.f / (1.f + __expf(-rg));
            float z = 1.f / (1.f + __expf(-zg));
            float na = ng + r * hold;
            float n = 1.f - 2.f / (1.f + __expf(2.f * na));   // tanh(na)
            float hn = (1.f - z) * n + z * hold;

            (cur ? h0f : h1f)[eoff] = hn;
            short hi, lo;
            split_bf16(hn, hi, lo);
            (cur ? h0hi : h1hi)[eoff] = hi;
            (cur ? h0lo : h1lo)[eoff] = lo;
            hs[((size_t)em * SS + t) * HH + ecol] = __float2bfloat16(hn);
        }
        __syncthreads();   // every wave's stores vmcnt-drained before signal

        // ---- 64-block mt-group barrier (round-3 semantics, bounded) ----
        if (tid == 0) {
            __threadfence();   // L2 writeback: publish h/hs to coherent point
            __hip_atomic_fetch_add(cnt_mt, 1, __ATOMIC_RELEASE, AGENT);
            const int target = 64 * (t + 1);
            int it = 0;
            while (it < (1 << 20)) {
                int v = ((it & 15) == 15)
                    ? __hip_atomic_load(cnt_mt, __ATOMIC_ACQUIRE, AGENT)
                    : __hip_atomic_load(cnt_mt, __ATOMIC_RELAXED, AGENT);
                if (v >= target) break;
                __builtin_amdgcn_s_sleep(2);
                ++it;
            }
            // one acquire (L1+L2 invalidate) before next step's h reads
            __hip_atomic_load(cnt_mt, __ATOMIC_ACQUIRE, AGENT);
        }
        __syncthreads();
    }
}

// ---------------------------------------------------------------------------
// Output GEMM via MFMA: out[B*S, O] = hs_bf16 @ (Wc_hi + Wc_lo) + bc.
// Block = 128x128 tile, 2x2 waves; each wave 4 m-frags x 4 jb, full K.
// ---------------------------------------------------------------------------
__global__ __launch_bounds__(256) void out_mfma(
    const short* __restrict__ Wct_hi, const short* __restrict__ Wct_lo,
    const __hip_bfloat16* __restrict__ hs,   // [B*S, H] bf16
    const float* __restrict__ bc, float* __restrict__ out)
{
    const int tid = threadIdx.x;
    const int lane = tid & 63;
    const int w = tid >> 6;
    const int nb = blockIdx.x & 7;
    const int mb = blockIdx.x >> 3;
    const int r0 = mb * 128 + (w & 1) * 64;     // wave row base
    const int jb0 = nb * 8 + (w >> 1) * 4;      // wave global-jb base
    const int kq = (lane >> 4) * 8;

    f32x4 acc[4][4];
#pragma unroll
    for (int i = 0; i < 4; ++i)
#pragma unroll
        for (int j = 0; j < 4; ++j) acc[i][j] = (f32x4){0.f, 0.f, 0.f, 0.f};

    const short* ar[4];
#pragma unroll
    for (int i = 0; i < 4; ++i)
        ar[i] = (const short*)hs +
                (size_t)(r0 + i * 16 + (lane & 15)) * HH + kq;

    for (int kt = 0; kt < 32; ++kt) {
        frag8 a[4];
#pragma unroll
        for (int i = 0; i < 4; ++i)
            a[i] = *(const frag8*)(ar[i] + kt * 32);
#pragma unroll
        for (int j = 0; j < 4; ++j) {
            size_t base = ((size_t)(jb0 + j) * 32 + kt) * 512 + (size_t)lane * 8;
            frag8 bhf = *(const frag8*)(Wct_hi + base);
            frag8 blf = *(const frag8*)(Wct_lo + base);
#pragma unroll
            for (int i = 0; i < 4; ++i) {
                acc[i][j] = MFMA_BF16(a[i], bhf, acc[i][j]);
                acc[i][j] = MFMA_BF16(a[i], blf, acc[i][j]);
            }
        }
    }

    const int lcol = lane & 15;
    const int rq = (lane >> 4) * 4;
#pragma unroll
    for (int j = 0; j < 4; ++j) {
        const int col = (jb0 + j) * 16 + lcol;
        const float bias = bc[col];
#pragma unroll
        for (int i = 0; i < 4; ++i) {
#pragma unroll
            for (int reg = 0; reg < 4; ++reg) {
                int row = r0 + i * 16 + rq + reg;
                out[(size_t)row * HH + col] = acc[i][j][reg] + bias;
            }
        }
    }
}

// ---------------------------------------------------------------------------
extern "C" void kernel_launch(void* const* d_in, const int* in_sizes, int n_in,
                              void* d_out, int out_size, void* d_ws, size_t ws_size,
                              hipStream_t stream) {
    const float* x  = (const float*)d_in[0];   // [B, S, D]
    const float* Wg = (const float*)d_in[1];   // [D+H, 3H]
    const float* bg = (const float*)d_in[2];   // [3H]
    const float* Wc = (const float*)d_in[3];   // [H, O]
    const float* bc = (const float*)d_in[4];   // [O]
    float* out = (float*)d_out;                // [B, S, O]

    // Workspace layout (~118.5 MB):
    //   hs    : [B,S,H] bf16                       67,108,864 B
    //   Wt_hi : [2048*3072] bf16 fragment order    12,582,912 B
    //   Wt_lo : same                               12,582,912 B
    //   2 x state set {h fp32, h_hi bf16, h_lo bf16} = 2 x 524,288 B
    //   gx    : [TCH, B, 3H] fp32                  25,165,824 B
    //   cnt   : 4 mt-group barrier counters, 128 B apart       512 B
    //   Wct_hi/Wct_lo (2 MB each) alias gx (gx dead after the loop).
    char* ws = (char*)d_ws;
    __hip_bfloat16* hs = (__hip_bfloat16*)ws;
    short* Wt_hi = (short*)(ws + 67108864);
    short* Wt_lo = (short*)(ws + 67108864 + 12582912);
    char* state = ws + 67108864 + 2 * 12582912;
    const size_t SET = 524288;
    float* gx = (float*)(state + 2 * SET);
    int* cnt = (int*)(state + 2 * SET + 25165824);
    short* Wct_hi = (short*)gx;                  // aliases gx (post-loop only)
    short* Wct_lo = Wct_hi + 1048576;

    float* hf[2];  short* hhi[2]; short* hlo[2];
    for (int p = 0; p < 2; ++p) {
        hf[p]  = (float*)(state + p * SET);
        hhi[p] = (short*)(state + p * SET + 262144);
        hlo[p] = (short*)(state + p * SET + 393216);
    }

    // zero the t=0 state set and the barrier counters (re-done every replay)
    hipMemsetAsync(state, 0, SET, stream);
    hipMemsetAsync(cnt, 0, 512, stream);

    prep_w<<<3072, 256, 0, stream>>>(Wg, Wt_hi, Wt_lo);

    for (int t0 = 0; t0 < SS; t0 += TCH) {
        gx_gemm<<<512, 256, 0, stream>>>(Wt_hi, Wt_lo, x, bg, gx, t0);

        const short* a0 = Wt_hi; const short* a1 = Wt_lo;
        const float* a2 = gx;
        float* a3 = hf[0]; short* a4 = hhi[0]; short* a5 = hlo[0];
        float* a6 = hf[1]; short* a7 = hhi[1]; short* a8 = hlo[1];
        __hip_bfloat16* a9 = hs; int* a10 = cnt; int a11 = t0;
        void* args[] = {&a0, &a1, &a2, &a3, &a4, &a5, &a6, &a7, &a8,
                        &a9, &a10, &a11};
        hipError_t ce = hipLaunchCooperativeKernel(
            gru_seg, dim3(256), dim3(512), args, 0, stream);
        if (ce != hipSuccess) {
            // fallback: plain launch — 256 blocks at 1 block/CU co-reside
            gru_seg<<<dim3(256), dim3(512), 0, stream>>>(
                a0, a1, a2, a3, a4, a5, a6, a7, a8, a9, a10, a11);
        }
    }

    {
        prep_wc<<<512, 256, 0, stream>>>(Wc, Wct_hi, Wct_lo);
        out_mfma<<<2048, 256, 0, stream>>>(Wct_hi, Wct_lo, hs, bc, out);
    }
}